// Round 1
// baseline (325.940 us; speedup 1.0000x reference)
//
#include <hip/hip_runtime.h>

// Problem constants (from reference)
#define N_NODES 2048
#define C_CH    128
#define NIRR    9
#define E_EL    10
// dslot mapping: 0 -> l0 (d=0), 1..3 -> l1 (d=0..2)
#define N3TAB (E_EL * 4 * 729 * C_CH)   // 3,732,480
#define N2TAB (E_EL * 4 * 81  * C_CH)   //   414,720
#define N1TAB (E_EL * 4 * 9   * C_CH)   //    46,080

__global__ __launch_bounds__(64) void zero_cnt_kernel(int* __restrict__ cnt) {
    if (threadIdx.x < 16) cnt[threadIdx.x] = 0;
}

// Find each node's element (one-hot) and bucket node ids by element.
__global__ __launch_bounds__(256) void bucket_kernel(const float* __restrict__ y,
                                                     int* __restrict__ cnt,
                                                     int* __restrict__ lists) {
    int b = blockIdx.x * 256 + threadIdx.x;
    if (b >= N_NODES) return;
    int e = 0;
    #pragma unroll
    for (int k = 1; k < E_EL; k++)
        if (y[b * E_EL + k] > 0.5f) e = k;
    int pos = atomicAdd(&cnt[e], 1);
    lists[e * N_NODES + pos] = b;
}

// Precompute per-(element, dslot, c) coupling tables:
//   U3w[e,ds,pqi,c] = sum_k u3[ds][pqi][k] * w3[e,k,c]   (K3=4)
//   U2w[e,ds,pq ,c] = sum_k u2[ds][pq ][k] * w2[e,k,c]   (K2=3)
//   U1w[e,ds,p  ,c] = sum_k u1[ds][p  ][k] * w1[e,k,c]   (K1=2)
__global__ __launch_bounds__(256) void build_tables_kernel(
    const float* __restrict__ u3_l0, const float* __restrict__ u2_l0, const float* __restrict__ u1_l0,
    const float* __restrict__ w3_l0, const float* __restrict__ w2_l0, const float* __restrict__ w1_l0,
    const float* __restrict__ u3_l1, const float* __restrict__ u2_l1, const float* __restrict__ u1_l1,
    const float* __restrict__ w3_l1, const float* __restrict__ w2_l1, const float* __restrict__ w1_l1,
    float* __restrict__ U3w, float* __restrict__ U2w, float* __restrict__ U1w)
{
    int idx = blockIdx.x * 256 + threadIdx.x;
    if (idx < N3TAB) {
        int c = idx & 127;
        int r = idx >> 7;
        int pqi = r % 729;
        int r2 = r / 729;
        int dslot = r2 & 3;
        int e = r2 >> 2;
        const float* u; const float* w;
        if (dslot == 0) { u = u3_l0 + pqi * 4;                     w = w3_l0 + e * 4 * 128 + c; }
        else            { u = u3_l1 + ((dslot - 1) * 729 + pqi) * 4; w = w3_l1 + e * 4 * 128 + c; }
        float acc = 0.f;
        #pragma unroll
        for (int k = 0; k < 4; k++) acc += u[k] * w[k * 128];
        U3w[idx] = acc;
    } else if (idx < N3TAB + N2TAB) {
        int idx2 = idx - N3TAB;
        int c = idx2 & 127;
        int r = idx2 >> 7;
        int pq = r % 81;
        int r2 = r / 81;
        int dslot = r2 & 3;
        int e = r2 >> 2;
        const float* u; const float* w;
        if (dslot == 0) { u = u2_l0 + pq * 3;                      w = w2_l0 + e * 3 * 128 + c; }
        else            { u = u2_l1 + ((dslot - 1) * 81 + pq) * 3; w = w2_l1 + e * 3 * 128 + c; }
        float acc = 0.f;
        #pragma unroll
        for (int k = 0; k < 3; k++) acc += u[k] * w[k * 128];
        U2w[idx2] = acc;
    } else if (idx < N3TAB + N2TAB + N1TAB) {
        int idx1 = idx - N3TAB - N2TAB;
        int c = idx1 & 127;
        int r = idx1 >> 7;
        int p = r % 9;
        int r2 = r / 9;
        int dslot = r2 & 3;
        int e = r2 >> 2;
        const float* u; const float* w;
        if (dslot == 0) { u = u1_l0 + p * 2;                      w = w1_l0 + e * 2 * 128 + c; }
        else            { u = u1_l1 + ((dslot - 1) * 9 + p) * 2; w = w1_l1 + e * 2 * 128 + c; }
        float acc = 0.f;
        #pragma unroll
        for (int k = 0; k < 2; k++) acc += u[k] * w[k * 128];
        U1w[idx1] = acc;
    }
}

// Main contraction. Block = 256 threads = (sub in {0,1}) x (c in [0,128)).
// Each block handles 8 nodes of one element (sub handles 4 nodes), so the
// table slice (1.68 MB per block over all c) is amortized 8x.
// Per (b,c,dslot): f = sum_p xv[p] * ( U1w[p] + sum_q xv[q] * ( U2w[p,q] + sum_i U3w[p,q,i]*xv[i] ) )
__global__ __launch_bounds__(256) void contract_kernel(
    const float* __restrict__ x,
    const float* __restrict__ U3w, const float* __restrict__ U2w, const float* __restrict__ U1w,
    const int* __restrict__ cnt, const int* __restrict__ lists,
    float* __restrict__ fbuf)
{
    int e = blockIdx.y;
    int count = cnt[e];
    int base0 = blockIdx.x * 8;
    if (base0 >= count) return;
    int tid = threadIdx.x;
    int c = tid & 127;
    int sub = tid >> 7;
    int base = base0 + sub * 4;

    int bnode[4];
    bool valid[4];
    #pragma unroll
    for (int j = 0; j < 4; j++) {
        int ii = base + j;
        valid[j] = (ii < count);
        bnode[j] = lists[e * N_NODES + (valid[j] ? ii : 0)];
    }

    float xv[4][9];
    #pragma unroll
    for (int j = 0; j < 4; j++) {
        const float* xp = x + ((size_t)bnode[j] * C_CH + c) * NIRR;
        #pragma unroll
        for (int i = 0; i < 9; i++) xv[j][i] = xp[i];
    }

    const float* t3 = U3w + (size_t)e * 4 * 729 * 128 + c;
    const float* t2 = U2w + (size_t)e * 4 * 81 * 128 + c;
    const float* t1 = U1w + (size_t)e * 4 * 9 * 128 + c;

    #pragma unroll 1
    for (int dslot = 0; dslot < 4; dslot++) {
        const float* p3 = t3 + dslot * 729 * 128;
        const float* p2 = t2 + dslot * 81 * 128;
        const float* p1 = t1 + dslot * 9 * 128;
        float facc[4] = {0.f, 0.f, 0.f, 0.f};
        int off3 = 0;
        int off2 = 0;
        #pragma unroll 1
        for (int p = 0; p < 9; p++) {
            float u1v = p1[p * 128];
            float B[4] = {u1v, u1v, u1v, u1v};
            #pragma unroll 3
            for (int q = 0; q < 9; q++) {
                float u2v = p2[off2];
                off2 += 128;
                float s[4] = {u2v, u2v, u2v, u2v};
                #pragma unroll
                for (int i = 0; i < 9; i++) {
                    float u = p3[off3 + i * 128];
                    #pragma unroll
                    for (int j = 0; j < 4; j++) s[j] += u * xv[j][i];
                }
                off3 += 9 * 128;
                #pragma unroll
                for (int j = 0; j < 4; j++) B[j] += s[j] * xv[j][q];
            }
            #pragma unroll
            for (int j = 0; j < 4; j++) facc[j] += B[j] * xv[j][p];
        }
        #pragma unroll
        for (int j = 0; j < 4; j++)
            if (valid[j]) fbuf[((size_t)dslot * N_NODES + bnode[j]) * C_CH + c] = facc[j];
    }
}

// Block-diagonal per-irrep channel mixing (o3.Linear) + skip connection.
// Block handles 8 consecutive nodes; f staged in LDS; each thread owns
// (j = out channel, two dslots), 8-node accumulator strip.
__global__ __launch_bounds__(256) void linear_kernel(
    const float* __restrict__ fbuf,
    const float* __restrict__ w0, const float* __restrict__ w1,
    const float* __restrict__ sc, float* __restrict__ out)
{
    __shared__ float fs[4 * 8 * 128];  // 16 KB
    int b0 = blockIdx.x * 8;
    int tid = threadIdx.x;
    for (int idx = tid; idx < 4096; idx += 256) {
        int m = idx >> 10;
        int rem = idx & 1023;
        int nb = rem >> 7;
        int i = rem & 127;
        fs[idx] = fbuf[((size_t)m * N_NODES + b0 + nb) * 128 + i];
    }
    __syncthreads();

    int j = tid & 127;
    int g = tid >> 7;
    const float inv_sqrt_c = 0.08838834764831845f;  // 1/sqrt(128)

    #pragma unroll
    for (int mm = 0; mm < 2; mm++) {
        int m = g + mm * 2;  // covers dslots {0,2} / {1,3}
        const float* w = (m == 0) ? w0 : w1;
        float acc[8];
        #pragma unroll
        for (int nb = 0; nb < 8; nb++) acc[nb] = 0.f;
        for (int i = 0; i < 128; i++) {
            float wv = w[i * 128 + j];
            #pragma unroll
            for (int nb = 0; nb < 8; nb++) acc[nb] += fs[m * 1024 + nb * 128 + i] * wv;
        }
        int col = (m == 0) ? j : (128 + j * 3 + (m - 1));
        #pragma unroll
        for (int nb = 0; nb < 8; nb++) {
            int oi = (b0 + nb) * 512 + col;
            out[oi] = acc[nb] * inv_sqrt_c + sc[oi];
        }
    }
}

extern "C" void kernel_launch(void* const* d_in, const int* in_sizes, int n_in,
                              void* d_out, int out_size, void* d_ws, size_t ws_size,
                              hipStream_t stream) {
    const float* x     = (const float*)d_in[0];
    const float* y     = (const float*)d_in[1];
    const float* sc    = (const float*)d_in[2];
    const float* u3_l0 = (const float*)d_in[3];
    const float* u2_l0 = (const float*)d_in[4];
    const float* u1_l0 = (const float*)d_in[5];
    const float* w3_l0 = (const float*)d_in[6];
    const float* w2_l0 = (const float*)d_in[7];
    const float* w1_l0 = (const float*)d_in[8];
    const float* u3_l1 = (const float*)d_in[9];
    const float* u2_l1 = (const float*)d_in[10];
    const float* u1_l1 = (const float*)d_in[11];
    const float* w3_l1 = (const float*)d_in[12];
    const float* w2_l1 = (const float*)d_in[13];
    const float* w1_l1 = (const float*)d_in[14];
    const float* lw0   = (const float*)d_in[15];
    const float* lw1   = (const float*)d_in[16];
    float* out = (float*)d_out;

    // Workspace layout (floats): U3w | U2w | U1w | fbuf | cnt(int) | lists(int)
    float* U3w  = (float*)d_ws;
    float* U2w  = U3w + N3TAB;
    float* U1w  = U2w + N2TAB;
    float* fbuf = U1w + N1TAB;
    int*   cnt  = (int*)(fbuf + (size_t)4 * N_NODES * C_CH);
    int*   lists = cnt + 16;

    zero_cnt_kernel<<<1, 64, 0, stream>>>(cnt);
    bucket_kernel<<<N_NODES / 256, 256, 0, stream>>>(y, cnt, lists);
    build_tables_kernel<<<(N3TAB + N2TAB + N1TAB) / 256, 256, 0, stream>>>(
        u3_l0, u2_l0, u1_l0, w3_l0, w2_l0, w1_l0,
        u3_l1, u2_l1, u1_l1, w3_l1, w2_l1, w1_l1,
        U3w, U2w, U1w);
    contract_kernel<<<dim3(N_NODES / 8, E_EL), 256, 0, stream>>>(
        x, U3w, U2w, U1w, cnt, lists, fbuf);
    linear_kernel<<<N_NODES / 8, 256, 0, stream>>>(fbuf, lw0, lw1, sc, out);
}

// Round 2
// 293.935 us; speedup vs baseline: 1.1089x; 1.1089x over previous
//
#include <hip/hip_runtime.h>

// Problem constants (from reference)
#define N_NODES 2048
#define C_CH    128
#define NIRR    9
#define E_EL    10
// dslot mapping: 0 -> l0 (d=0), 1..3 -> l1 (d=0..2)

// Padded-vector table layouts (pad 9 -> 12 floats so each lane reads 3 float4):
//   U3w: [e][ds][pq(81)][c(128)][i(12)]
//   U2w: [e][ds][p(9)][c(128)][q(12)]
//   U1w: [e][ds][c(128)][p(12)]
#define N3TAB (E_EL * 4 * 81 * 128 * 12)   // 4,976,640 floats
#define N2TAB (E_EL * 4 * 9  * 128 * 12)   //   552,960
#define N1TAB (E_EL * 4 *      128 * 12)   //    61,440

__global__ __launch_bounds__(64) void zero_cnt_kernel(int* __restrict__ cnt) {
    if (threadIdx.x < 16) cnt[threadIdx.x] = 0;
}

// Find each node's element (one-hot) and bucket node ids by element.
__global__ __launch_bounds__(256) void bucket_kernel(const float* __restrict__ y,
                                                     int* __restrict__ cnt,
                                                     int* __restrict__ lists) {
    int b = blockIdx.x * 256 + threadIdx.x;
    if (b >= N_NODES) return;
    int e = 0;
    #pragma unroll
    for (int k = 1; k < E_EL; k++)
        if (y[b * E_EL + k] > 0.5f) e = k;
    int pos = atomicAdd(&cnt[e], 1);
    lists[e * N_NODES + pos] = b;
}

// Precompute per-(element, dslot, c) coupling tables in padded i-innermost layout.
__global__ __launch_bounds__(256) void build_tables_kernel(
    const float* __restrict__ u3_l0, const float* __restrict__ u2_l0, const float* __restrict__ u1_l0,
    const float* __restrict__ w3_l0, const float* __restrict__ w2_l0, const float* __restrict__ w1_l0,
    const float* __restrict__ u3_l1, const float* __restrict__ u2_l1, const float* __restrict__ u1_l1,
    const float* __restrict__ w3_l1, const float* __restrict__ w2_l1, const float* __restrict__ w1_l1,
    float* __restrict__ U3w, float* __restrict__ U2w, float* __restrict__ U1w)
{
    int idx = blockIdx.x * 256 + threadIdx.x;
    if (idx < N3TAB) {
        int i = idx % 12;
        int r = idx / 12;
        int c = r & 127;
        r >>= 7;
        int pq = r % 81;
        int r2 = r / 81;
        int ds = r2 & 3;
        int e = r2 >> 2;
        float acc = 0.f;
        if (i < 9) {
            int pqi = pq * 9 + i;
            const float* u; const float* w;
            if (ds == 0) { u = u3_l0 + pqi * 4;                     w = w3_l0 + e * 4 * 128 + c; }
            else         { u = u3_l1 + ((ds - 1) * 729 + pqi) * 4; w = w3_l1 + e * 4 * 128 + c; }
            #pragma unroll
            for (int k = 0; k < 4; k++) acc += u[k] * w[k * 128];
        }
        U3w[idx] = acc;
    } else if (idx < N3TAB + N2TAB) {
        int idx2 = idx - N3TAB;
        int q = idx2 % 12;
        int r = idx2 / 12;
        int c = r & 127;
        r >>= 7;
        int p = r % 9;
        int r2 = r / 9;
        int ds = r2 & 3;
        int e = r2 >> 2;
        float acc = 0.f;
        if (q < 9) {
            int pq = p * 9 + q;
            const float* u; const float* w;
            if (ds == 0) { u = u2_l0 + pq * 3;                     w = w2_l0 + e * 3 * 128 + c; }
            else         { u = u2_l1 + ((ds - 1) * 81 + pq) * 3;  w = w2_l1 + e * 3 * 128 + c; }
            #pragma unroll
            for (int k = 0; k < 3; k++) acc += u[k] * w[k * 128];
        }
        U2w[idx2] = acc;
    } else if (idx < N3TAB + N2TAB + N1TAB) {
        int idx1 = idx - N3TAB - N2TAB;
        int p = idx1 % 12;
        int r = idx1 / 12;
        int c = r & 127;
        r >>= 7;
        int ds = r & 3;
        int e = r >> 2;
        float acc = 0.f;
        if (p < 9) {
            const float* u; const float* w;
            if (ds == 0) { u = u1_l0 + p * 2;                     w = w1_l0 + e * 2 * 128 + c; }
            else         { u = u1_l1 + ((ds - 1) * 9 + p) * 2;   w = w1_l1 + e * 2 * 128 + c; }
            #pragma unroll
            for (int k = 0; k < 2; k++) acc += u[k] * w[k * 128];
        }
        U1w[idx1] = acc;
    }
}

// Main contraction. grid = (nodes/8, E, 4 dslots); block = 2 subs x 128 c.
// Each thread handles 4 nodes of one element for one dslot.
// Per (b,c): f = sum_p xv[p] * ( U1w[p] + sum_q xv[q] * ( U2w[p,q] + sum_i U3w[p,q,i]*xv[i] ) )
__global__ __launch_bounds__(256) void contract_kernel(
    const float* __restrict__ x,
    const float* __restrict__ U3w, const float* __restrict__ U2w, const float* __restrict__ U1w,
    const int* __restrict__ cnt, const int* __restrict__ lists,
    float* __restrict__ fbuf)
{
    int e = blockIdx.y;
    int ds = blockIdx.z;
    int count = cnt[e];
    int base0 = blockIdx.x * 8;
    if (base0 >= count) return;
    int tid = threadIdx.x;
    int c = tid & 127;
    int sub = tid >> 7;
    int base = base0 + sub * 4;

    int bnode[4];
    bool valid[4];
    #pragma unroll
    for (int j = 0; j < 4; j++) {
        int ii = base + j;
        valid[j] = (ii < count);
        bnode[j] = lists[e * N_NODES + (valid[j] ? ii : 0)];
    }

    float xv[4][9];
    #pragma unroll
    for (int j = 0; j < 4; j++) {
        const float* xp = x + ((size_t)bnode[j] * C_CH + c) * NIRR;
        #pragma unroll
        for (int i = 0; i < 9; i++) xv[j][i] = xp[i];
    }

    int eds = e * 4 + ds;
    const float4* __restrict__ p3 = (const float4*)U3w + ((size_t)eds * 81 * 128 + c) * 3;
    const float4* __restrict__ p2 = (const float4*)U2w + ((size_t)eds * 9 * 128 + c) * 3;
    const float4* __restrict__ p1 = (const float4*)U1w + ((size_t)eds * 128 + c) * 3;

    // u1 strip for this lane (9 values over p)
    float4 u1a = p1[0], u1b = p1[1], u1c = p1[2];
    float u1arr[9] = {u1a.x, u1a.y, u1a.z, u1a.w, u1b.x, u1b.y, u1b.z, u1b.w, u1c.x};

    float facc[4] = {0.f, 0.f, 0.f, 0.f};

    #pragma unroll 1
    for (int p = 0; p < 9; p++) {
        float4 q2a = p2[(size_t)p * 384];
        float4 q2b = p2[(size_t)p * 384 + 1];
        float4 q2c = p2[(size_t)p * 384 + 2];
        float u2arr[9] = {q2a.x, q2a.y, q2a.z, q2a.w, q2b.x, q2b.y, q2b.z, q2b.w, q2c.x};
        float B[4] = {u1arr[p], u1arr[p], u1arr[p], u1arr[p]};
        #pragma unroll 3
        for (int q = 0; q < 9; q++) {
            size_t o = (size_t)(p * 9 + q) * 384;
            float4 a0 = p3[o];
            float4 a1 = p3[o + 1];
            float4 a2 = p3[o + 2];
            #pragma unroll
            for (int j = 0; j < 4; j++) {
                float s = u2arr[q];
                s += a0.x * xv[j][0];
                s += a0.y * xv[j][1];
                s += a0.z * xv[j][2];
                s += a0.w * xv[j][3];
                s += a1.x * xv[j][4];
                s += a1.y * xv[j][5];
                s += a1.z * xv[j][6];
                s += a1.w * xv[j][7];
                s += a2.x * xv[j][8];
                B[j] += s * xv[j][q];
            }
        }
        #pragma unroll
        for (int j = 0; j < 4; j++) facc[j] += B[j] * xv[j][p];
    }
    #pragma unroll
    for (int j = 0; j < 4; j++)
        if (valid[j]) fbuf[((size_t)ds * N_NODES + bnode[j]) * C_CH + c] = facc[j];
}

// Block-diagonal per-irrep channel mixing (o3.Linear) + skip connection.
__global__ __launch_bounds__(256) void linear_kernel(
    const float* __restrict__ fbuf,
    const float* __restrict__ w0, const float* __restrict__ w1,
    const float* __restrict__ sc, float* __restrict__ out)
{
    __shared__ float fs[4 * 8 * 128];  // 16 KB
    int b0 = blockIdx.x * 8;
    int tid = threadIdx.x;
    for (int idx = tid; idx < 4096; idx += 256) {
        int m = idx >> 10;
        int rem = idx & 1023;
        int nb = rem >> 7;
        int i = rem & 127;
        fs[idx] = fbuf[((size_t)m * N_NODES + b0 + nb) * 128 + i];
    }
    __syncthreads();

    int j = tid & 127;
    int g = tid >> 7;
    const float inv_sqrt_c = 0.08838834764831845f;  // 1/sqrt(128)

    #pragma unroll
    for (int mm = 0; mm < 2; mm++) {
        int m = g + mm * 2;  // covers dslots {0,2} / {1,3}
        const float* w = (m == 0) ? w0 : w1;
        float acc[8];
        #pragma unroll
        for (int nb = 0; nb < 8; nb++) acc[nb] = 0.f;
        for (int i = 0; i < 128; i++) {
            float wv = w[i * 128 + j];
            #pragma unroll
            for (int nb = 0; nb < 8; nb++) acc[nb] += fs[m * 1024 + nb * 128 + i] * wv;
        }
        int col = (m == 0) ? j : (128 + j * 3 + (m - 1));
        #pragma unroll
        for (int nb = 0; nb < 8; nb++) {
            int oi = (b0 + nb) * 512 + col;
            out[oi] = acc[nb] * inv_sqrt_c + sc[oi];
        }
    }
}

extern "C" void kernel_launch(void* const* d_in, const int* in_sizes, int n_in,
                              void* d_out, int out_size, void* d_ws, size_t ws_size,
                              hipStream_t stream) {
    const float* x     = (const float*)d_in[0];
    const float* y     = (const float*)d_in[1];
    const float* sc    = (const float*)d_in[2];
    const float* u3_l0 = (const float*)d_in[3];
    const float* u2_l0 = (const float*)d_in[4];
    const float* u1_l0 = (const float*)d_in[5];
    const float* w3_l0 = (const float*)d_in[6];
    const float* w2_l0 = (const float*)d_in[7];
    const float* w1_l0 = (const float*)d_in[8];
    const float* u3_l1 = (const float*)d_in[9];
    const float* u2_l1 = (const float*)d_in[10];
    const float* u1_l1 = (const float*)d_in[11];
    const float* w3_l1 = (const float*)d_in[12];
    const float* w2_l1 = (const float*)d_in[13];
    const float* w1_l1 = (const float*)d_in[14];
    const float* lw0   = (const float*)d_in[15];
    const float* lw1   = (const float*)d_in[16];
    float* out = (float*)d_out;

    // Workspace layout (floats): U3w | U2w | U1w | fbuf | cnt(int) | lists(int)
    float* U3w  = (float*)d_ws;
    float* U2w  = U3w + N3TAB;
    float* U1w  = U2w + N2TAB;
    float* fbuf = U1w + N1TAB;
    int*   cnt  = (int*)(fbuf + (size_t)4 * N_NODES * C_CH);
    int*   lists = cnt + 16;

    zero_cnt_kernel<<<1, 64, 0, stream>>>(cnt);
    bucket_kernel<<<N_NODES / 256, 256, 0, stream>>>(y, cnt, lists);
    int tot = N3TAB + N2TAB + N1TAB;
    build_tables_kernel<<<(tot + 255) / 256, 256, 0, stream>>>(
        u3_l0, u2_l0, u1_l0, w3_l0, w2_l0, w1_l0,
        u3_l1, u2_l1, u1_l1, w3_l1, w2_l1, w1_l1,
        U3w, U2w, U1w);
    contract_kernel<<<dim3(N_NODES / 8, E_EL, 4), 256, 0, stream>>>(
        x, U3w, U2w, U1w, cnt, lists, fbuf);
    linear_kernel<<<N_NODES / 8, 256, 0, stream>>>(fbuf, lw0, lw1, sc, out);
}

// Round 3
// 251.748 us; speedup vs baseline: 1.2947x; 1.1676x over previous
//
#include <hip/hip_runtime.h>

// Problem constants (from reference)
#define N_NODES 2048
#define C_CH    128
#define NIRR    9
#define E_EL    10
// dslot mapping: 0 -> l0 (d=0), 1..3 -> l1 (d=0..2)

// Padded-vector table layouts (pad 9 -> 12 floats so each lane reads 3 float4):
//   U3w: [e][ds][pq(81)][c(128)][i(12)]
//   U2w: [e][ds][p(9)][c(128)][q(12)]
//   U1w: [e][ds][c(128)][p(12)]
#define N3TAB (E_EL * 4 * 81 * 128 * 12)   // 4,976,640 floats
#define N2TAB (E_EL * 4 * 9  * 128 * 12)   //   552,960
#define N1TAB (E_EL * 4 *      128 * 12)   //    61,440

__global__ __launch_bounds__(64) void zero_cnt_kernel(int* __restrict__ cnt) {
    if (threadIdx.x < 16) cnt[threadIdx.x] = 0;
}

// Find each node's element (one-hot) and bucket node ids by element.
__global__ __launch_bounds__(256) void bucket_kernel(const float* __restrict__ y,
                                                     int* __restrict__ cnt,
                                                     int* __restrict__ lists) {
    int b = blockIdx.x * 256 + threadIdx.x;
    if (b >= N_NODES) return;
    int e = 0;
    #pragma unroll
    for (int k = 1; k < E_EL; k++)
        if (y[b * E_EL + k] > 0.5f) e = k;
    int pos = atomicAdd(&cnt[e], 1);
    lists[e * N_NODES + pos] = b;
}

// Precompute per-(element, dslot, c) coupling tables in padded i-innermost layout.
__global__ __launch_bounds__(256) void build_tables_kernel(
    const float* __restrict__ u3_l0, const float* __restrict__ u2_l0, const float* __restrict__ u1_l0,
    const float* __restrict__ w3_l0, const float* __restrict__ w2_l0, const float* __restrict__ w1_l0,
    const float* __restrict__ u3_l1, const float* __restrict__ u2_l1, const float* __restrict__ u1_l1,
    const float* __restrict__ w3_l1, const float* __restrict__ w2_l1, const float* __restrict__ w1_l1,
    float* __restrict__ U3w, float* __restrict__ U2w, float* __restrict__ U1w)
{
    int idx = blockIdx.x * 256 + threadIdx.x;
    if (idx < N3TAB) {
        int i = idx % 12;
        int r = idx / 12;
        int c = r & 127;
        r >>= 7;
        int pq = r % 81;
        int r2 = r / 81;
        int ds = r2 & 3;
        int e = r2 >> 2;
        float acc = 0.f;
        if (i < 9) {
            int pqi = pq * 9 + i;
            const float* u; const float* w;
            if (ds == 0) { u = u3_l0 + pqi * 4;                     w = w3_l0 + e * 4 * 128 + c; }
            else         { u = u3_l1 + ((ds - 1) * 729 + pqi) * 4; w = w3_l1 + e * 4 * 128 + c; }
            #pragma unroll
            for (int k = 0; k < 4; k++) acc += u[k] * w[k * 128];
        }
        U3w[idx] = acc;
    } else if (idx < N3TAB + N2TAB) {
        int idx2 = idx - N3TAB;
        int q = idx2 % 12;
        int r = idx2 / 12;
        int c = r & 127;
        r >>= 7;
        int p = r % 9;
        int r2 = r / 9;
        int ds = r2 & 3;
        int e = r2 >> 2;
        float acc = 0.f;
        if (q < 9) {
            int pq = p * 9 + q;
            const float* u; const float* w;
            if (ds == 0) { u = u2_l0 + pq * 3;                     w = w2_l0 + e * 3 * 128 + c; }
            else         { u = u2_l1 + ((ds - 1) * 81 + pq) * 3;  w = w2_l1 + e * 3 * 128 + c; }
            #pragma unroll
            for (int k = 0; k < 3; k++) acc += u[k] * w[k * 128];
        }
        U2w[idx2] = acc;
    } else if (idx < N3TAB + N2TAB + N1TAB) {
        int idx1 = idx - N3TAB - N2TAB;
        int p = idx1 % 12;
        int r = idx1 / 12;
        int c = r & 127;
        r >>= 7;
        int ds = r & 3;
        int e = r >> 2;
        float acc = 0.f;
        if (p < 9) {
            const float* u; const float* w;
            if (ds == 0) { u = u1_l0 + p * 2;                     w = w1_l0 + e * 2 * 128 + c; }
            else         { u = u1_l1 + ((ds - 1) * 9 + p) * 2;   w = w1_l1 + e * 2 * 128 + c; }
            #pragma unroll
            for (int k = 0; k < 2; k++) acc += u[k] * w[k * 128];
        }
        U1w[idx1] = acc;
    }
}

// Main contraction. 1D grid of 2560 blocks, XCD-aware decode:
//   xcd = bid & 7, rest = bid >> 3, slot = rest >> 6, blk = rest & 63
//   slice s = slot*8 + xcd  ->  e = s>>2, ds = s&3
// All blocks touching slice s satisfy bid % 8 == s % 8, i.e. land on one XCD
// (empirical round-robin dispatch) -> each XCD's 5 slices (~2.5 MB) stay
// L2-resident. Grid-stride loop over 512-node chunks for any element dist.
__global__ __launch_bounds__(256) void contract_kernel(
    const float* __restrict__ x,
    const float* __restrict__ U3w, const float* __restrict__ U2w, const float* __restrict__ U1w,
    const int* __restrict__ cnt, const int* __restrict__ lists,
    float* __restrict__ fbuf)
{
    int bid = blockIdx.x;
    int xcd = bid & 7;
    int rest = bid >> 3;
    int slot = rest >> 6;
    int blk = rest & 63;
    int s = slot * 8 + xcd;     // 0..39
    int e = s >> 2;
    int ds = s & 3;
    int count = cnt[e];

    int tid = threadIdx.x;
    int c = tid & 127;
    int sub = tid >> 7;

    int eds = e * 4 + ds;
    const float4* __restrict__ p3 = (const float4*)U3w + ((size_t)eds * 81 * 128 + c) * 3;
    const float4* __restrict__ p2 = (const float4*)U2w + ((size_t)eds * 9 * 128 + c) * 3;
    const float4* __restrict__ p1 = (const float4*)U1w + ((size_t)eds * 128 + c) * 3;

    // u1 strip for this lane (9 values over p)
    float4 u1a = p1[0], u1b = p1[1], u1c = p1[2];
    float u1arr[9] = {u1a.x, u1a.y, u1a.z, u1a.w, u1b.x, u1b.y, u1b.z, u1b.w, u1c.x};

    for (int base0 = blk * 8; base0 < count; base0 += 512) {
        int base = base0 + sub * 4;

        int bnode[4];
        bool valid[4];
        #pragma unroll
        for (int j = 0; j < 4; j++) {
            int ii = base + j;
            valid[j] = (ii < count);
            bnode[j] = lists[e * N_NODES + (valid[j] ? ii : 0)];
        }

        float xv[4][9];
        #pragma unroll
        for (int j = 0; j < 4; j++) {
            const float* xp = x + ((size_t)bnode[j] * C_CH + c) * NIRR;
            #pragma unroll
            for (int i = 0; i < 9; i++) xv[j][i] = xp[i];
        }

        float facc[4] = {0.f, 0.f, 0.f, 0.f};

        #pragma unroll 1
        for (int p = 0; p < 9; p++) {
            float4 q2a = p2[(size_t)p * 384];
            float4 q2b = p2[(size_t)p * 384 + 1];
            float4 q2c = p2[(size_t)p * 384 + 2];
            float u2arr[9] = {q2a.x, q2a.y, q2a.z, q2a.w, q2b.x, q2b.y, q2b.z, q2b.w, q2c.x};
            float B[4] = {u1arr[p], u1arr[p], u1arr[p], u1arr[p]};
            #pragma unroll 3
            for (int q = 0; q < 9; q++) {
                size_t o = (size_t)(p * 9 + q) * 384;
                float4 a0 = p3[o];
                float4 a1 = p3[o + 1];
                float4 a2 = p3[o + 2];
                #pragma unroll
                for (int j = 0; j < 4; j++) {
                    float sj = u2arr[q];
                    sj += a0.x * xv[j][0];
                    sj += a0.y * xv[j][1];
                    sj += a0.z * xv[j][2];
                    sj += a0.w * xv[j][3];
                    sj += a1.x * xv[j][4];
                    sj += a1.y * xv[j][5];
                    sj += a1.z * xv[j][6];
                    sj += a1.w * xv[j][7];
                    sj += a2.x * xv[j][8];
                    B[j] += sj * xv[j][q];
                }
            }
            #pragma unroll
            for (int j = 0; j < 4; j++) facc[j] += B[j] * xv[j][p];
        }
        #pragma unroll
        for (int j = 0; j < 4; j++)
            if (valid[j]) fbuf[((size_t)ds * N_NODES + bnode[j]) * C_CH + c] = facc[j];
    }
}

// Block-diagonal per-irrep channel mixing (o3.Linear) + skip connection.
__global__ __launch_bounds__(256) void linear_kernel(
    const float* __restrict__ fbuf,
    const float* __restrict__ w0, const float* __restrict__ w1,
    const float* __restrict__ sc, float* __restrict__ out)
{
    __shared__ float fs[4 * 8 * 128];  // 16 KB
    int b0 = blockIdx.x * 8;
    int tid = threadIdx.x;
    for (int idx = tid; idx < 4096; idx += 256) {
        int m = idx >> 10;
        int rem = idx & 1023;
        int nb = rem >> 7;
        int i = rem & 127;
        fs[idx] = fbuf[((size_t)m * N_NODES + b0 + nb) * 128 + i];
    }
    __syncthreads();

    int j = tid & 127;
    int g = tid >> 7;
    const float inv_sqrt_c = 0.08838834764831845f;  // 1/sqrt(128)

    #pragma unroll
    for (int mm = 0; mm < 2; mm++) {
        int m = g + mm * 2;  // covers dslots {0,2} / {1,3}
        const float* w = (m == 0) ? w0 : w1;
        float acc[8];
        #pragma unroll
        for (int nb = 0; nb < 8; nb++) acc[nb] = 0.f;
        for (int i = 0; i < 128; i++) {
            float wv = w[i * 128 + j];
            #pragma unroll
            for (int nb = 0; nb < 8; nb++) acc[nb] += fs[m * 1024 + nb * 128 + i] * wv;
        }
        int col = (m == 0) ? j : (128 + j * 3 + (m - 1));
        #pragma unroll
        for (int nb = 0; nb < 8; nb++) {
            int oi = (b0 + nb) * 512 + col;
            out[oi] = acc[nb] * inv_sqrt_c + sc[oi];
        }
    }
}

extern "C" void kernel_launch(void* const* d_in, const int* in_sizes, int n_in,
                              void* d_out, int out_size, void* d_ws, size_t ws_size,
                              hipStream_t stream) {
    const float* x     = (const float*)d_in[0];
    const float* y     = (const float*)d_in[1];
    const float* sc    = (const float*)d_in[2];
    const float* u3_l0 = (const float*)d_in[3];
    const float* u2_l0 = (const float*)d_in[4];
    const float* u1_l0 = (const float*)d_in[5];
    const float* w3_l0 = (const float*)d_in[6];
    const float* w2_l0 = (const float*)d_in[7];
    const float* w1_l0 = (const float*)d_in[8];
    const float* u3_l1 = (const float*)d_in[9];
    const float* u2_l1 = (const float*)d_in[10];
    const float* u1_l1 = (const float*)d_in[11];
    const float* w3_l1 = (const float*)d_in[12];
    const float* w2_l1 = (const float*)d_in[13];
    const float* w1_l1 = (const float*)d_in[14];
    const float* lw0   = (const float*)d_in[15];
    const float* lw1   = (const float*)d_in[16];
    float* out = (float*)d_out;

    // Workspace layout (floats): U3w | U2w | U1w | fbuf | cnt(int) | lists(int)
    float* U3w  = (float*)d_ws;
    float* U2w  = U3w + N3TAB;
    float* U1w  = U2w + N2TAB;
    float* fbuf = U1w + N1TAB;
    int*   cnt  = (int*)(fbuf + (size_t)4 * N_NODES * C_CH);
    int*   lists = cnt + 16;

    zero_cnt_kernel<<<1, 64, 0, stream>>>(cnt);
    bucket_kernel<<<N_NODES / 256, 256, 0, stream>>>(y, cnt, lists);
    int tot = N3TAB + N2TAB + N1TAB;
    build_tables_kernel<<<(tot + 255) / 256, 256, 0, stream>>>(
        u3_l0, u2_l0, u1_l0, w3_l0, w2_l0, w1_l0,
        u3_l1, u2_l1, u1_l1, w3_l1, w2_l1, w1_l1,
        U3w, U2w, U1w);
    contract_kernel<<<2560, 256, 0, stream>>>(
        x, U3w, U2w, U1w, cnt, lists, fbuf);
    linear_kernel<<<N_NODES / 8, 256, 0, stream>>>(fbuf, lw0, lw1, sc, out);
}